// Round 20
// baseline (203.437 us; speedup 1.0000x reference)
//
#include <hip/hip_runtime.h>
#include <math.h>

namespace {

constexpr int kB = 16, kT = 32, kN = 64, kE = 64, kFIN = 2, kD = 64, kH = 4, kL = 2, kSH = 128;
constexpr int kG = kB * kT;    // 512 graphs
constexpr int kET = kE + kN;   // 128 edges incl. self loops

// ---------------- GAT LDS (BYTE offsets, ONE graph per 512-thread block) ----------------
// f16 tiles swizzled: (row,dd) -> row*64 + ((dd>>3)^(row&7))*8 + (dd&7)
constexpr int O_HN = 0;          // h    f16 [64][64] swz (8192 B)
constexpr int O_XL = 8192;       // xl   f16 [4][64][64] swz (32768 B)
constexpr int O_XR = 40960;      // xr   f16 [4][64][64] swz (32768 B)
constexpr int O_LG = 73728;      // logit f32 [4][128] (2048 B)
constexpr int O_MB = 75776;      // max   f32 [4][64] (1024 B)
constexpr int O_SB = 76800;      // 1/sum f32 [4][64] (1024 B)
constexpr int O_IB = 77824;      // ints [449] (1796 B)
constexpr size_t GAT_LDS = O_IB + 449 * 4;   // 79,620 B -> 2 blocks/CU (159.2 KB)
constexpr int ISRC = 0, IDST = 128, IOFF = 256, IEL = 321;

// ---------------- LSTM LDS layout (float/u32 indices) — R19 unit-local form ----------------
constexpr int ES   = 0;                    // emb f32 [32][64]; reused as head scratch
constexpr int EMPK = ES + 2048;            // packed emb u32 [32][32]
constexpr int YSPK = EMPK + 1024;          // packed ys  u32 [32][64]
constexpr int ZX   = YSPK + 2048;          // zx f32 [32][512]
constexpr int HBF  = ZX + 32 * 512;        // h f32 [128]
constexpr int GBF  = HBF + 128;            // f,o gates f32 [2][128]
constexpr int LSTM_FLOATS = GBF + 256;
constexpr size_t LSTM_LDS = size_t(LSTM_FLOATS) * 4;  // 87,552 B

typedef _Float16 half8  __attribute__((ext_vector_type(8)));
typedef _Float16 half2v __attribute__((ext_vector_type(2)));
typedef float    f32x4  __attribute__((ext_vector_type(4)));

__device__ __forceinline__ float fsig(float x) {
    return __builtin_amdgcn_rcpf(1.f + __expf(-x));
}
__device__ __forceinline__ float ftanh(float x) {
    return 1.f - 2.f * __builtin_amdgcn_rcpf(1.f + __expf(2.f * x));
}
__device__ __forceinline__ unsigned pk16(float a, float b) {
    return __builtin_bit_cast(unsigned, __builtin_amdgcn_cvt_pkrtz(a, b));
}
__device__ __forceinline__ unsigned rlu(unsigned v, int l) {
    return (unsigned)__builtin_amdgcn_readlane((int)v, l);
}
__device__ __forceinline__ float fdot2(unsigned a, unsigned b, float c) {
    return __builtin_amdgcn_fdot2(__builtin_bit_cast(half2v, a),
                                  __builtin_bit_cast(half2v, b), c, false);
}
__device__ __forceinline__ int swz(int row, int dd) {
    return row * 64 + (((dd >> 3) ^ (row & 7)) << 3) + (dd & 7);
}

} // namespace

// =====================================================================
// GAT kernel: ONE graph per 512-thread block, 512 blocks, 79.6 KB LDS
// -> 2 blocks/CU, ONE round. All 4 heads per phase: wave wv = (matrix
// wv&1, head wv>>1) computes a full 64x64 transform (acc[4][4] f32x4).
// Alpha folded into aggregate (inline exp). 4 phases/layer.
// =====================================================================
__global__ __launch_bounds__(512, 4)   // cap VGPR at 128 for 2 blocks/CU
void gat_kernel(const float* __restrict__ x, const int* __restrict__ eidx,
                const float* __restrict__ projW, const float* __restrict__ projb,
                const float* __restrict__ gWl, const float* __restrict__ gWr,
                const float* __restrict__ gatt, const float* __restrict__ gb,
                const float* __restrict__ lng, const float* __restrict__ lnb,
                float* __restrict__ emb)
{
    extern __shared__ char smc[];
    _Float16* hn  = (_Float16*)(smc + O_HN);
    _Float16* xlh = (_Float16*)(smc + O_XL);
    _Float16* xrh = (_Float16*)(smc + O_XR);
    float* lg  = (float*)(smc + O_LG);
    float* mb  = (float*)(smc + O_MB);
    float* sb  = (float*)(smc + O_SB);
    int*   ib  = (int*)(smc + O_IB);
    const int g  = blockIdx.x;
    const int tl = threadIdx.x;      // 0..511

    // ---- edges + self loops ----
    if (tl < kET) {
        int s, d;
        if (tl < kE) { s = eidx[g * 2 * kE + tl]; d = eidx[g * 2 * kE + kE + tl]; }
        else         { s = tl - kE; d = s; }
        ib[ISRC + tl] = s;
        ib[IDST + tl] = d;
    }
    // ---- input projection + ReLU -> h (f16, swz) ----
    #pragma unroll
    for (int r = 0; r < 8; ++r) {
        int p = tl + 512 * r;
        int d = p & 63, n = p >> 6;
        float x0 = x[g * kN * kFIN + n * kFIN + 0];
        float x1 = x[g * kN * kFIN + n * kFIN + 1];
        float v = fmaf(x0, projW[d * kFIN + 0], fmaf(x1, projW[d * kFIN + 1], projb[d]));
        hn[swz(n, d)] = (_Float16)fmaxf(v, 0.f);
    }
    __syncthreads();
    // ---- CSR build: count + wave shfl_up scan ----
    if (tl < kN) {
        int c = 0;
        for (int e = 0; e < kET; ++e) c += (ib[IDST + e] == tl) ? 1 : 0;
        int s = c;
        #pragma unroll
        for (int d = 1; d < 64; d <<= 1) {
            int v = __shfl_up(s, d);
            if (tl >= d) s += v;
        }
        ib[IOFF + tl + 1] = s;
        if (tl == 0) ib[IOFF + 0] = 0;
    }
    __syncthreads();
    if (tl < kN) {
        int pos = ib[IOFF + tl];
        for (int e = 0; e < kET; ++e)
            if (ib[IDST + e] == tl) ib[IEL + pos++] = e;
    }
    __syncthreads();

    const int wv = tl >> 6;       // wave 0..7
    const int ln = tl & 63;
    const int mt = wv & 1;        // 0 -> xl, 1 -> xr
    const int hw = wv >> 1;       // head 0..3 owned by this wave (transform)
    const int lr = ln & 15;       // A-row / B-col within 16-tile
    const int kg = ln >> 4;       // k-chunk group 0..3
    _Float16* tdst = (mt ? xrh : xlh) + hw * 4096;

    for (int l = 0; l < kL; ++l) {
        // ---- phase 1: transform — wave computes full 64x64 for (mt, hw) ----
        {
            const float* Wg = (mt ? gWr : gWl) + l * 256 * 64 + hw * 64 * 64;
            f32x4 acc[4][4];
            #pragma unroll
            for (int tn = 0; tn < 4; ++tn)
                #pragma unroll
                for (int tc = 0; tc < 4; ++tc) acc[tn][tc] = (f32x4){0.f,0.f,0.f,0.f};
            #pragma unroll
            for (int q = 0; q < 2; ++q) {
                const int kc = q * 4 + kg;
                half8 af[4];
                #pragma unroll
                for (int tn = 0; tn < 4; ++tn)
                    af[tn] = *(const half8*)&hn[(16 * tn + lr) * 64 + ((kc ^ (lr & 7)) << 3)];
                #pragma unroll
                for (int tc = 0; tc < 4; ++tc) {
                    const float* wp = Wg + (16 * tc + lr) * 64 + kc * 8;
                    float4 wu = *(const float4*)wp;
                    float4 wz = *(const float4*)(wp + 4);
                    half8 bf;
                    bf[0] = (_Float16)wu.x; bf[1] = (_Float16)wu.y;
                    bf[2] = (_Float16)wu.z; bf[3] = (_Float16)wu.w;
                    bf[4] = (_Float16)wz.x; bf[5] = (_Float16)wz.y;
                    bf[6] = (_Float16)wz.z; bf[7] = (_Float16)wz.w;
                    #pragma unroll
                    for (int tn = 0; tn < 4; ++tn)
                        acc[tn][tc] = __builtin_amdgcn_mfma_f32_16x16x32_f16(af[tn], bf, acc[tn][tc], 0, 0, 0);
                }
            }
            #pragma unroll
            for (int tn = 0; tn < 4; ++tn)
                #pragma unroll
                for (int tc = 0; tc < 4; ++tc) {
                    const int dd = 16 * tc + lr;
                    #pragma unroll
                    for (int r = 0; r < 4; ++r) {
                        const int n = 16 * tn + kg * 4 + r;
                        tdst[swz(n, dd)] = (_Float16)acc[tn][tc][r];
                    }
                }
        }
        __syncthreads();
        // ---- phase 2: edge logits — all 512 threads, (e, head) ----
        {
            const int e = tl & 127, hq = tl >> 7;   // head 0..3
            const int s = ib[ISRC + e], d_ = ib[IDST + e];
            const float* av = gatt + (l * kH + hq) * kD;
            float a0 = 0.f, a1 = 0.f, a2 = 0.f, a3 = 0.f;
            #pragma unroll
            for (int c8 = 0; c8 < 8; ++c8) {
                half8 xv = *(const half8*)&xlh[hq * 4096 + s  * 64 + ((c8 ^ (s  & 7)) << 3)];
                half8 rv = *(const half8*)&xrh[hq * 4096 + d_ * 64 + ((c8 ^ (d_ & 7)) << 3)];
                float4 au = *(const float4*)(av + c8 * 8);
                float4 az = *(const float4*)(av + c8 * 8 + 4);
                const float avv[8] = {au.x, au.y, au.z, au.w, az.x, az.y, az.z, az.w};
                #pragma unroll
                for (int i = 0; i < 8; ++i) {
                    float v = (float)xv[i] + (float)rv[i];
                    v = (v > 0.f) ? v : 0.2f * v;
                    float* a = (i & 2) ? ((i & 1) ? &a3 : &a2) : ((i & 1) ? &a1 : &a0);
                    *a = fmaf(avv[i], v, *a);
                }
            }
            lg[hq * 128 + e] = (a0 + a1) + (a2 + a3);
        }
        __syncthreads();
        // ---- phase 3: segment max & sum — 256 threads (n, head) ----
        if (tl < 256) {
            const int n = tl & 63, hq = tl >> 6;
            const int i0 = ib[IOFF + n], i1 = ib[IOFF + n + 1];
            float m = -3.0e38f;
            for (int i = i0; i < i1; ++i) m = fmaxf(m, lg[hq * 128 + ib[IEL + i]]);
            float ssum = 0.f;
            for (int i = i0; i < i1; ++i) ssum += __expf(lg[hq * 128 + ib[IEL + i]] - m);
            mb[hq * 64 + n] = m;
            sb[hq * 64 + n] = __builtin_amdgcn_rcpf(ssum);
        }
        __syncthreads();
        // ---- phase 4: aggregate (inline alpha) + head-mean + LN + ReLU ----
        #pragma unroll
        for (int r = 0; r < 8; ++r) {
            int p = tl + 512 * r;
            int n = p >> 6, dd = p & 63;      // n wave-uniform, dd = lane
            const int i0 = ib[IOFF + n], i1 = ib[IOFF + n + 1];
            const float mb0 = mb[n], mb1 = mb[64 + n], mb2 = mb[128 + n], mb3 = mb[192 + n];
            const float sb0 = sb[n], sb1 = sb[64 + n], sb2 = sb[128 + n], sb3 = sb[192 + n];
            float acc = 0.f;
            for (int i = i0; i < i1; ++i) {
                int e = ib[IEL + i];
                int s = ib[ISRC + e];
                int si = swz(s, dd);
                float a0 = __expf(lg[e]       - mb0) * sb0;
                float a1 = __expf(lg[128 + e] - mb1) * sb1;
                float a2 = __expf(lg[256 + e] - mb2) * sb2;
                float a3 = __expf(lg[384 + e] - mb3) * sb3;
                acc = fmaf(a0, (float)xlh[si],         acc);
                acc = fmaf(a1, (float)xlh[4096 + si],  acc);
                acc = fmaf(a2, (float)xlh[8192 + si],  acc);
                acc = fmaf(a3, (float)xlh[12288 + si], acc);
            }
            float v = acc * 0.25f + gb[l * kD + dd];
            float s1 = v, s2 = v * v;
            #pragma unroll
            for (int m = 1; m < 64; m <<= 1) {
                s1 += __shfl_xor(s1, m);
                s2 += __shfl_xor(s2, m);
            }
            float mu  = s1 * (1.f / 64.f);
            float var = s2 * (1.f / 64.f) - mu * mu;
            float rs  = rsqrtf(var + 1e-5f);
            float y   = fmaf(lng[l * kD + dd] * (v - mu), rs, lnb[l * kD + dd]);
            hn[swz(n, dd)] = (_Float16)fmaxf(y, 0.f);
        }
        __syncthreads();
    } // layer
    // ---- global mean pool ----
    if (tl < kD) {
        float s = 0.f;
        #pragma unroll 8
        for (int n = 0; n < kN; ++n) s += (float)hn[swz(n, tl)];
        emb[g * kD + tl] = s * (1.f / 64.f);
    }
}

// =====================================================================
// LSTM (2 layers, T=32) + MLP head (UNCHANGED from R19): one block per
// batch (16), 256 threads, unit-local gates, 2x 4-wave barriers/step.
// =====================================================================
__global__ __launch_bounds__(256, 1)
void lstm_head_kernel(const float* __restrict__ emb,
                      const float* __restrict__ W0ih, const float* __restrict__ W0hh,
                      const float* __restrict__ b0ih, const float* __restrict__ b0hh,
                      const float* __restrict__ W1ih, const float* __restrict__ W1hh,
                      const float* __restrict__ b1ih, const float* __restrict__ b1hh,
                      const float* __restrict__ hW1, const float* __restrict__ hb1,
                      const float* __restrict__ hW2, const float* __restrict__ hb2,
                      const float* __restrict__ hW3, const float* __restrict__ hb3,
                      float* __restrict__ outp)
{
    extern __shared__ float sm[];
    unsigned* smu = (unsigned*)sm;
    const int bb   = blockIdx.x;
    const int j    = threadIdx.x;     // 0..255
    const int ln   = j & 63;
    const int rowA = j;               // i(j) for j<128, f(j-128) for j>=128
    const int rowB = j + 256;         // g(j) for j<128, o(j-128) for j>=128

    ((float4*)(sm + ES))[j]       = ((const float4*)(emb + bb * kT * kD))[j];
    ((float4*)(sm + ES))[j + 256] = ((const float4*)(emb + bb * kT * kD))[j + 256];
    __syncthreads();
    #pragma unroll
    for (int r = 0; r < 4; ++r) {
        int w = j + 256 * r;
        int tt = w >> 5, i = w & 31;
        smu[EMPK + w] = pk16(sm[ES + tt * 64 + 2 * i], sm[ES + tt * 64 + 2 * i + 1]);
    }
    __syncthreads();

    // ---- layer0 x-part ----
    {
        unsigned wA[32], wB[32];
        const float4* ra = (const float4*)(W0ih + rowA * 64);
        const float4* rb = (const float4*)(W0ih + rowB * 64);
        #pragma unroll
        for (int k4 = 0; k4 < 16; ++k4) {
            float4 a = ra[k4], b = rb[k4];
            wA[2*k4] = pk16(a.x, a.y); wA[2*k4+1] = pk16(a.z, a.w);
            wB[2*k4] = pk16(b.x, b.y); wB[2*k4+1] = pk16(b.z, b.w);
        }
        const float biasA = b0ih[rowA] + b0hh[rowA];
        const float biasB = b0ih[rowB] + b0hh[rowB];
        for (int tt = 0; tt < kT; ++tt) {
            unsigned ev = smu[EMPK + tt * 32 + (ln & 31)];
            float a0 = biasA, a1 = 0.f, b0 = biasB, b1 = 0.f;
            #pragma unroll
            for (int q = 0; q < 32; q += 2) {
                unsigned e0 = rlu(ev, q), e1 = rlu(ev, q + 1);
                a0 = fdot2(wA[q],     e0, a0);
                a1 = fdot2(wA[q + 1], e1, a1);
                b0 = fdot2(wB[q],     e0, b0);
                b1 = fdot2(wB[q + 1], e1, b1);
            }
            sm[ZX + tt * 512 + rowA] = a0 + a1;
            sm[ZX + tt * 512 + rowB] = b0 + b1;
        }
    }
    __syncthreads();
    // ---- layer0 recurrence (unit-local gates) ----
    {
        unsigned wA[64], wB[64];
        const float4* ra = (const float4*)(W0hh + rowA * 128);
        const float4* rb = (const float4*)(W0hh + rowB * 128);
        #pragma unroll
        for (int k4 = 0; k4 < 32; ++k4) {
            float4 a = ra[k4], b = rb[k4];
            wA[2*k4] = pk16(a.x, a.y); wA[2*k4+1] = pk16(a.z, a.w);
            wB[2*k4] = pk16(b.x, b.y); wB[2*k4+1] = pk16(b.z, b.w);
        }
        unsigned hpk = 0;
        float c = 0.f;
        for (int tt = 0; tt < kT; ++tt) {
            float a0 = sm[ZX + tt * 512 + rowA], a1 = 0.f;
            float b0 = sm[ZX + tt * 512 + rowB], b1 = 0.f;
            #pragma unroll
            for (int q = 0; q < 64; q += 2) {
                unsigned h0 = rlu(hpk, q), h1 = rlu(hpk, q + 1);
                a0 = fdot2(wA[q],     h0, a0);
                a1 = fdot2(wA[q + 1], h1, a1);
                b0 = fdot2(wB[q],     h0, b0);
                b1 = fdot2(wB[q + 1], h1, b1);
            }
            float zA = a0 + a1, zB = b0 + b1;
            float gi = 0.f, gg = 0.f;
            if (j < 128) { gi = fsig(zA); gg = ftanh(zB); }
            else         { sm[GBF + (j - 128)] = fsig(zA); sm[GBF + 128 + (j - 128)] = fsig(zB); }
            __syncthreads();
            if (j < 128) {
                float f = sm[GBF + j], o = sm[GBF + 128 + j];
                c = fmaf(f, c, gi * gg);
                sm[HBF + j] = o * ftanh(c);
            }
            __syncthreads();
            hpk = pk16(sm[HBF + 2 * ln], sm[HBF + 2 * ln + 1]);
            if (j < 64) smu[YSPK + tt * 64 + ln] = hpk;
        }
    }
    __syncthreads();
    // ---- layer1 x-part ----
    {
        unsigned wA[64], wB[64];
        const float4* ra = (const float4*)(W1ih + rowA * 128);
        const float4* rb = (const float4*)(W1ih + rowB * 128);
        #pragma unroll
        for (int k4 = 0; k4 < 32; ++k4) {
            float4 a = ra[k4], b = rb[k4];
            wA[2*k4] = pk16(a.x, a.y); wA[2*k4+1] = pk16(a.z, a.w);
            wB[2*k4] = pk16(b.x, b.y); wB[2*k4+1] = pk16(b.z, b.w);
        }
        const float biasA = b1ih[rowA] + b1hh[rowA];
        const float biasB = b1ih[rowB] + b1hh[rowB];
        for (int tt = 0; tt < kT; ++tt) {
            unsigned yv = smu[YSPK + tt * 64 + ln];
            float a0 = biasA, a1 = 0.f, b0 = biasB, b1 = 0.f;
            #pragma unroll
            for (int q = 0; q < 64; q += 2) {
                unsigned y0 = rlu(yv, q), y1 = rlu(yv, q + 1);
                a0 = fdot2(wA[q],     y0, a0);
                a1 = fdot2(wA[q + 1], y1, a1);
                b0 = fdot2(wB[q],     y0, b0);
                b1 = fdot2(wB[q + 1], y1, b1);
            }
            sm[ZX + tt * 512 + rowA] = a0 + a1;
            sm[ZX + tt * 512 + rowB] = b0 + b1;
        }
    }
    __syncthreads();
    // ---- layer1 recurrence (final h left in HBF) ----
    {
        unsigned wA[64], wB[64];
        const float4* ra = (const float4*)(W1hh + rowA * 128);
        const float4* rb = (const float4*)(W1hh + rowB * 128);
        #pragma unroll
        for (int k4 = 0; k4 < 32; ++k4) {
            float4 a = ra[k4], b = rb[k4];
            wA[2*k4] = pk16(a.x, a.y); wA[2*k4+1] = pk16(a.z, a.w);
            wB[2*k4] = pk16(b.x, b.y); wB[2*k4+1] = pk16(b.z, b.w);
        }
        unsigned hpk = 0;
        float c = 0.f;
        for (int tt = 0; tt < kT; ++tt) {
            float a0 = sm[ZX + tt * 512 + rowA], a1 = 0.f;
            float b0 = sm[ZX + tt * 512 + rowB], b1 = 0.f;
            #pragma unroll
            for (int q = 0; q < 64; q += 2) {
                unsigned h0 = rlu(hpk, q), h1 = rlu(hpk, q + 1);
                a0 = fdot2(wA[q],     h0, a0);
                a1 = fdot2(wA[q + 1], h1, a1);
                b0 = fdot2(wB[q],     h0, b0);
                b1 = fdot2(wB[q + 1], h1, b1);
            }
            float zA = a0 + a1, zB = b0 + b1;
            float gi = 0.f, gg = 0.f;
            if (j < 128) { gi = fsig(zA); gg = ftanh(zB); }
            else         { sm[GBF + (j - 128)] = fsig(zA); sm[GBF + 128 + (j - 128)] = fsig(zB); }
            __syncthreads();
            if (j < 128) {
                float f = sm[GBF + j], o = sm[GBF + 128 + j];
                c = fmaf(f, c, gi * gg);
                sm[HBF + j] = o * ftanh(c);
            }
            __syncthreads();
            hpk = pk16(sm[HBF + 2 * ln], sm[HBF + 2 * ln + 1]);
        }
    }
    // ---- MLP head ----
    if (j < 64) {
        float a0 = hb1[j], a1 = 0.f;
        #pragma unroll 8
        for (int k = 0; k < 128; k += 2) {
            a0 = fmaf(hW1[j * 128 + k],     sm[HBF + k],     a0);
            a1 = fmaf(hW1[j * 128 + k + 1], sm[HBF + k + 1], a1);
        }
        sm[ES + j] = fmaxf(a0 + a1, 0.f);
    }
    __syncthreads();
    if (j < 32) {
        float acc = hb2[j];
        #pragma unroll 8
        for (int k = 0; k < 64; ++k) acc = fmaf(hW2[j * 64 + k], sm[ES + k], acc);
        sm[ES + 64 + j] = fmaxf(acc, 0.f);
    }
    __syncthreads();
    if (j == 0) {
        float acc = hb3[0];
        #pragma unroll
        for (int k = 0; k < 32; ++k) acc = fmaf(hW3[k], sm[ES + 64 + k], acc);
        outp[bb] = fsig(acc);
    }
}

extern "C" void kernel_launch(void* const* d_in, const int* in_sizes, int n_in,
                              void* d_out, int out_size, void* d_ws, size_t ws_size,
                              hipStream_t stream) {
    const float* x     = (const float*)d_in[0];
    const int*   eidx  = (const int*)  d_in[1];
    const float* projW = (const float*)d_in[2];
    const float* projb = (const float*)d_in[3];
    const float* gWl   = (const float*)d_in[4];
    const float* gWr   = (const float*)d_in[5];
    const float* gatt  = (const float*)d_in[6];
    const float* gb    = (const float*)d_in[7];
    const float* lng   = (const float*)d_in[8];
    const float* lnb   = (const float*)d_in[9];
    const float* W0ih  = (const float*)d_in[10];
    const float* W0hh  = (const float*)d_in[11];
    const float* b0ih  = (const float*)d_in[12];
    const float* b0hh  = (const float*)d_in[13];
    const float* W1ih  = (const float*)d_in[14];
    const float* W1hh  = (const float*)d_in[15];
    const float* b1ih  = (const float*)d_in[16];
    const float* b1hh  = (const float*)d_in[17];
    const float* hW1   = (const float*)d_in[18];
    const float* hb1   = (const float*)d_in[19];
    const float* hW2   = (const float*)d_in[20];
    const float* hb2   = (const float*)d_in[21];
    const float* hW3   = (const float*)d_in[22];
    const float* hb3   = (const float*)d_in[23];
    float* outp = (float*)d_out;
    float* emb  = (float*)d_ws;   // [512][64] fp32 scratch

    (void)hipFuncSetAttribute((const void*)gat_kernel,
                              hipFuncAttributeMaxDynamicSharedMemorySize, (int)GAT_LDS);
    (void)hipFuncSetAttribute((const void*)lstm_head_kernel,
                              hipFuncAttributeMaxDynamicSharedMemorySize, (int)LSTM_LDS);

    hipLaunchKernelGGL(gat_kernel, dim3(kG), dim3(512), GAT_LDS, stream,
                       x, eidx, projW, projb, gWl, gWr, gatt, gb, lng, lnb, emb);
    hipLaunchKernelGGL(lstm_head_kernel, dim3(kB), dim3(256), LSTM_LDS, stream,
                       emb, W0ih, W0hh, b0ih, b0hh, W1ih, W1hh, b1ih, b1hh,
                       hW1, hb1, hW2, hb2, hW3, hb3, outp);
}

// Round 21
// 172.583 us; speedup vs baseline: 1.1788x; 1.1788x over previous
//
#include <hip/hip_runtime.h>
#include <math.h>

namespace {

constexpr int kB = 16, kT = 32, kN = 64, kE = 64, kFIN = 2, kD = 64, kH = 4, kL = 2, kSH = 128;
constexpr int kG = kB * kT;    // 512 graphs
constexpr int kET = kE + kN;   // 128 edges incl. self loops

// ---------------- GAT LDS (BYTE offsets, ONE graph per 512-thread block) ----------------
constexpr int O_HN = 0;          // h    f16 [64][64] swz (8192 B)
constexpr int O_XL = 8192;       // xl   f16 [4][64][64] swz (32768 B)
constexpr int O_XR = 40960;      // xr   f16 [4][64][64] swz (32768 B)
constexpr int O_LG = 73728;      // logit f32 [4][128] (2048 B)
constexpr int O_MB = 75776;      // max   f32 [4][64] (1024 B)
constexpr int O_SB = 76800;      // 1/sum f32 [4][64] (1024 B)
constexpr int O_IB = 77824;      // ints [449] (1796 B)
constexpr size_t GAT_LDS = O_IB + 449 * 4;   // 79,620 B -> 2 blocks/CU (159.2 KB)
constexpr int ISRC = 0, IDST = 128, IOFF = 256, IEL = 321;

// ---------------- LSTM LDS layout (float/u32 indices) — R19 unit-local form ----------------
constexpr int ES   = 0;                    // emb f32 [32][64]; reused as head scratch
constexpr int EMPK = ES + 2048;            // packed emb u32 [32][32]
constexpr int YSPK = EMPK + 1024;          // packed ys  u32 [32][64]
constexpr int ZX   = YSPK + 2048;          // zx f32 [32][512]
constexpr int HBF  = ZX + 32 * 512;        // h f32 [128]
constexpr int GBF  = HBF + 128;            // f,o gates f32 [2][128]
constexpr int LSTM_FLOATS = GBF + 256;
constexpr size_t LSTM_LDS = size_t(LSTM_FLOATS) * 4;  // 87,552 B

typedef _Float16 half8  __attribute__((ext_vector_type(8)));
typedef _Float16 half2v __attribute__((ext_vector_type(2)));
typedef float    f32x4  __attribute__((ext_vector_type(4)));

__device__ __forceinline__ float fsig(float x) {
    return __builtin_amdgcn_rcpf(1.f + __expf(-x));
}
__device__ __forceinline__ float ftanh(float x) {
    return 1.f - 2.f * __builtin_amdgcn_rcpf(1.f + __expf(2.f * x));
}
__device__ __forceinline__ unsigned pk16(float a, float b) {
    return __builtin_bit_cast(unsigned, __builtin_amdgcn_cvt_pkrtz(a, b));
}
__device__ __forceinline__ unsigned rlu(unsigned v, int l) {
    return (unsigned)__builtin_amdgcn_readlane((int)v, l);
}
__device__ __forceinline__ float fdot2(unsigned a, unsigned b, float c) {
    return __builtin_amdgcn_fdot2(__builtin_bit_cast(half2v, a),
                                  __builtin_bit_cast(half2v, b), c, false);
}
__device__ __forceinline__ int swz(int row, int dd) {
    return row * 64 + (((dd >> 3) ^ (row & 7)) << 3) + (dd & 7);
}

} // namespace

// =====================================================================
// GAT kernel: ONE graph per 512-thread block, 512 blocks, 79.6 KB LDS.
// R20 proved 2 blocks/CU co-residency; launch_bounds(512,1) lets the
// allocator keep acc[4][4] in registers (R20's (512,4) forced 64 VGPR
// -> 153+153 MB scratch spill). Target: ~110-125 VGPR, no spill.
// =====================================================================
__global__ __launch_bounds__(512, 1)
void gat_kernel(const float* __restrict__ x, const int* __restrict__ eidx,
                const float* __restrict__ projW, const float* __restrict__ projb,
                const float* __restrict__ gWl, const float* __restrict__ gWr,
                const float* __restrict__ gatt, const float* __restrict__ gb,
                const float* __restrict__ lng, const float* __restrict__ lnb,
                float* __restrict__ emb)
{
    extern __shared__ char smc[];
    _Float16* hn  = (_Float16*)(smc + O_HN);
    _Float16* xlh = (_Float16*)(smc + O_XL);
    _Float16* xrh = (_Float16*)(smc + O_XR);
    float* lg  = (float*)(smc + O_LG);
    float* mb  = (float*)(smc + O_MB);
    float* sb  = (float*)(smc + O_SB);
    int*   ib  = (int*)(smc + O_IB);
    const int g  = blockIdx.x;
    const int tl = threadIdx.x;      // 0..511

    // ---- edges + self loops ----
    if (tl < kET) {
        int s, d;
        if (tl < kE) { s = eidx[g * 2 * kE + tl]; d = eidx[g * 2 * kE + kE + tl]; }
        else         { s = tl - kE; d = s; }
        ib[ISRC + tl] = s;
        ib[IDST + tl] = d;
    }
    // ---- input projection + ReLU -> h (f16, swz) ----
    #pragma unroll
    for (int r = 0; r < 8; ++r) {
        int p = tl + 512 * r;
        int d = p & 63, n = p >> 6;
        float x0 = x[g * kN * kFIN + n * kFIN + 0];
        float x1 = x[g * kN * kFIN + n * kFIN + 1];
        float v = fmaf(x0, projW[d * kFIN + 0], fmaf(x1, projW[d * kFIN + 1], projb[d]));
        hn[swz(n, d)] = (_Float16)fmaxf(v, 0.f);
    }
    __syncthreads();
    // ---- CSR build: count + wave shfl_up scan ----
    if (tl < kN) {
        int c = 0;
        for (int e = 0; e < kET; ++e) c += (ib[IDST + e] == tl) ? 1 : 0;
        int s = c;
        #pragma unroll
        for (int d = 1; d < 64; d <<= 1) {
            int v = __shfl_up(s, d);
            if (tl >= d) s += v;
        }
        ib[IOFF + tl + 1] = s;
        if (tl == 0) ib[IOFF + 0] = 0;
    }
    __syncthreads();
    if (tl < kN) {
        int pos = ib[IOFF + tl];
        for (int e = 0; e < kET; ++e)
            if (ib[IDST + e] == tl) ib[IEL + pos++] = e;
    }
    __syncthreads();

    const int wv = tl >> 6;       // wave 0..7
    const int ln = tl & 63;
    const int mt = wv & 1;        // 0 -> xl, 1 -> xr
    const int hw = wv >> 1;       // head 0..3 owned by this wave (transform)
    const int lr = ln & 15;       // A-row / B-col within 16-tile
    const int kg = ln >> 4;       // k-chunk group 0..3
    _Float16* tdst = (mt ? xrh : xlh) + hw * 4096;

    for (int l = 0; l < kL; ++l) {
        // ---- phase 1: transform — wave computes full 64x64 for (mt, hw) ----
        {
            const float* Wg = (mt ? gWr : gWl) + l * 256 * 64 + hw * 64 * 64;
            f32x4 acc[4][4];
            #pragma unroll
            for (int tn = 0; tn < 4; ++tn)
                #pragma unroll
                for (int tc = 0; tc < 4; ++tc) acc[tn][tc] = (f32x4){0.f,0.f,0.f,0.f};
            #pragma unroll
            for (int q = 0; q < 2; ++q) {
                const int kc = q * 4 + kg;
                half8 af[4];
                #pragma unroll
                for (int tn = 0; tn < 4; ++tn)
                    af[tn] = *(const half8*)&hn[(16 * tn + lr) * 64 + ((kc ^ (lr & 7)) << 3)];
                #pragma unroll
                for (int tc = 0; tc < 4; ++tc) {
                    const float* wp = Wg + (16 * tc + lr) * 64 + kc * 8;
                    float4 wu = *(const float4*)wp;
                    float4 wz = *(const float4*)(wp + 4);
                    half8 bf;
                    bf[0] = (_Float16)wu.x; bf[1] = (_Float16)wu.y;
                    bf[2] = (_Float16)wu.z; bf[3] = (_Float16)wu.w;
                    bf[4] = (_Float16)wz.x; bf[5] = (_Float16)wz.y;
                    bf[6] = (_Float16)wz.z; bf[7] = (_Float16)wz.w;
                    #pragma unroll
                    for (int tn = 0; tn < 4; ++tn)
                        acc[tn][tc] = __builtin_amdgcn_mfma_f32_16x16x32_f16(af[tn], bf, acc[tn][tc], 0, 0, 0);
                }
            }
            #pragma unroll
            for (int tn = 0; tn < 4; ++tn)
                #pragma unroll
                for (int tc = 0; tc < 4; ++tc) {
                    const int dd = 16 * tc + lr;
                    #pragma unroll
                    for (int r = 0; r < 4; ++r) {
                        const int n = 16 * tn + kg * 4 + r;
                        tdst[swz(n, dd)] = (_Float16)acc[tn][tc][r];
                    }
                }
        }
        __syncthreads();
        // ---- phase 2: edge logits — all 512 threads, (e, head) ----
        {
            const int e = tl & 127, hq = tl >> 7;   // head 0..3
            const int s = ib[ISRC + e], d_ = ib[IDST + e];
            const float* av = gatt + (l * kH + hq) * kD;
            float a0 = 0.f, a1 = 0.f, a2 = 0.f, a3 = 0.f;
            #pragma unroll
            for (int c8 = 0; c8 < 8; ++c8) {
                half8 xv = *(const half8*)&xlh[hq * 4096 + s  * 64 + ((c8 ^ (s  & 7)) << 3)];
                half8 rv = *(const half8*)&xrh[hq * 4096 + d_ * 64 + ((c8 ^ (d_ & 7)) << 3)];
                float4 au = *(const float4*)(av + c8 * 8);
                float4 az = *(const float4*)(av + c8 * 8 + 4);
                const float avv[8] = {au.x, au.y, au.z, au.w, az.x, az.y, az.z, az.w};
                #pragma unroll
                for (int i = 0; i < 8; ++i) {
                    float v = (float)xv[i] + (float)rv[i];
                    v = (v > 0.f) ? v : 0.2f * v;
                    float* a = (i & 2) ? ((i & 1) ? &a3 : &a2) : ((i & 1) ? &a1 : &a0);
                    *a = fmaf(avv[i], v, *a);
                }
            }
            lg[hq * 128 + e] = (a0 + a1) + (a2 + a3);
        }
        __syncthreads();
        // ---- phase 3: segment max & sum — 256 threads (n, head) ----
        if (tl < 256) {
            const int n = tl & 63, hq = tl >> 6;
            const int i0 = ib[IOFF + n], i1 = ib[IOFF + n + 1];
            float m = -3.0e38f;
            for (int i = i0; i < i1; ++i) m = fmaxf(m, lg[hq * 128 + ib[IEL + i]]);
            float ssum = 0.f;
            for (int i = i0; i < i1; ++i) ssum += __expf(lg[hq * 128 + ib[IEL + i]] - m);
            mb[hq * 64 + n] = m;
            sb[hq * 64 + n] = __builtin_amdgcn_rcpf(ssum);
        }
        __syncthreads();
        // ---- phase 4: aggregate (inline alpha) + head-mean + LN + ReLU ----
        #pragma unroll
        for (int r = 0; r < 8; ++r) {
            int p = tl + 512 * r;
            int n = p >> 6, dd = p & 63;      // n wave-uniform, dd = lane
            const int i0 = ib[IOFF + n], i1 = ib[IOFF + n + 1];
            const float mb0 = mb[n], mb1 = mb[64 + n], mb2 = mb[128 + n], mb3 = mb[192 + n];
            const float sb0 = sb[n], sb1 = sb[64 + n], sb2 = sb[128 + n], sb3 = sb[192 + n];
            float acc = 0.f;
            for (int i = i0; i < i1; ++i) {
                int e = ib[IEL + i];
                int s = ib[ISRC + e];
                int si = swz(s, dd);
                float a0 = __expf(lg[e]       - mb0) * sb0;
                float a1 = __expf(lg[128 + e] - mb1) * sb1;
                float a2 = __expf(lg[256 + e] - mb2) * sb2;
                float a3 = __expf(lg[384 + e] - mb3) * sb3;
                acc = fmaf(a0, (float)xlh[si],         acc);
                acc = fmaf(a1, (float)xlh[4096 + si],  acc);
                acc = fmaf(a2, (float)xlh[8192 + si],  acc);
                acc = fmaf(a3, (float)xlh[12288 + si], acc);
            }
            float v = acc * 0.25f + gb[l * kD + dd];
            float s1 = v, s2 = v * v;
            #pragma unroll
            for (int m = 1; m < 64; m <<= 1) {
                s1 += __shfl_xor(s1, m);
                s2 += __shfl_xor(s2, m);
            }
            float mu  = s1 * (1.f / 64.f);
            float var = s2 * (1.f / 64.f) - mu * mu;
            float rs  = rsqrtf(var + 1e-5f);
            float y   = fmaf(lng[l * kD + dd] * (v - mu), rs, lnb[l * kD + dd]);
            hn[swz(n, dd)] = (_Float16)fmaxf(y, 0.f);
        }
        __syncthreads();
    } // layer
    // ---- global mean pool ----
    if (tl < kD) {
        float s = 0.f;
        #pragma unroll 8
        for (int n = 0; n < kN; ++n) s += (float)hn[swz(n, tl)];
        emb[g * kD + tl] = s * (1.f / 64.f);
    }
}

// =====================================================================
// LSTM (2 layers, T=32) + MLP head (UNCHANGED from R19): one block per
// batch (16), 256 threads, unit-local gates, 2x 4-wave barriers/step.
// =====================================================================
__global__ __launch_bounds__(256, 1)
void lstm_head_kernel(const float* __restrict__ emb,
                      const float* __restrict__ W0ih, const float* __restrict__ W0hh,
                      const float* __restrict__ b0ih, const float* __restrict__ b0hh,
                      const float* __restrict__ W1ih, const float* __restrict__ W1hh,
                      const float* __restrict__ b1ih, const float* __restrict__ b1hh,
                      const float* __restrict__ hW1, const float* __restrict__ hb1,
                      const float* __restrict__ hW2, const float* __restrict__ hb2,
                      const float* __restrict__ hW3, const float* __restrict__ hb3,
                      float* __restrict__ outp)
{
    extern __shared__ float sm[];
    unsigned* smu = (unsigned*)sm;
    const int bb   = blockIdx.x;
    const int j    = threadIdx.x;     // 0..255
    const int ln   = j & 63;
    const int rowA = j;               // i(j) for j<128, f(j-128) for j>=128
    const int rowB = j + 256;         // g(j) for j<128, o(j-128) for j>=128

    ((float4*)(sm + ES))[j]       = ((const float4*)(emb + bb * kT * kD))[j];
    ((float4*)(sm + ES))[j + 256] = ((const float4*)(emb + bb * kT * kD))[j + 256];
    __syncthreads();
    #pragma unroll
    for (int r = 0; r < 4; ++r) {
        int w = j + 256 * r;
        int tt = w >> 5, i = w & 31;
        smu[EMPK + w] = pk16(sm[ES + tt * 64 + 2 * i], sm[ES + tt * 64 + 2 * i + 1]);
    }
    __syncthreads();

    // ---- layer0 x-part ----
    {
        unsigned wA[32], wB[32];
        const float4* ra = (const float4*)(W0ih + rowA * 64);
        const float4* rb = (const float4*)(W0ih + rowB * 64);
        #pragma unroll
        for (int k4 = 0; k4 < 16; ++k4) {
            float4 a = ra[k4], b = rb[k4];
            wA[2*k4] = pk16(a.x, a.y); wA[2*k4+1] = pk16(a.z, a.w);
            wB[2*k4] = pk16(b.x, b.y); wB[2*k4+1] = pk16(b.z, b.w);
        }
        const float biasA = b0ih[rowA] + b0hh[rowA];
        const float biasB = b0ih[rowB] + b0hh[rowB];
        for (int tt = 0; tt < kT; ++tt) {
            unsigned ev = smu[EMPK + tt * 32 + (ln & 31)];
            float a0 = biasA, a1 = 0.f, b0 = biasB, b1 = 0.f;
            #pragma unroll
            for (int q = 0; q < 32; q += 2) {
                unsigned e0 = rlu(ev, q), e1 = rlu(ev, q + 1);
                a0 = fdot2(wA[q],     e0, a0);
                a1 = fdot2(wA[q + 1], e1, a1);
                b0 = fdot2(wB[q],     e0, b0);
                b1 = fdot2(wB[q + 1], e1, b1);
            }
            sm[ZX + tt * 512 + rowA] = a0 + a1;
            sm[ZX + tt * 512 + rowB] = b0 + b1;
        }
    }
    __syncthreads();
    // ---- layer0 recurrence (unit-local gates) ----
    {
        unsigned wA[64], wB[64];
        const float4* ra = (const float4*)(W0hh + rowA * 128);
        const float4* rb = (const float4*)(W0hh + rowB * 128);
        #pragma unroll
        for (int k4 = 0; k4 < 32; ++k4) {
            float4 a = ra[k4], b = rb[k4];
            wA[2*k4] = pk16(a.x, a.y); wA[2*k4+1] = pk16(a.z, a.w);
            wB[2*k4] = pk16(b.x, b.y); wB[2*k4+1] = pk16(b.z, b.w);
        }
        unsigned hpk = 0;
        float c = 0.f;
        for (int tt = 0; tt < kT; ++tt) {
            float a0 = sm[ZX + tt * 512 + rowA], a1 = 0.f;
            float b0 = sm[ZX + tt * 512 + rowB], b1 = 0.f;
            #pragma unroll
            for (int q = 0; q < 64; q += 2) {
                unsigned h0 = rlu(hpk, q), h1 = rlu(hpk, q + 1);
                a0 = fdot2(wA[q],     h0, a0);
                a1 = fdot2(wA[q + 1], h1, a1);
                b0 = fdot2(wB[q],     h0, b0);
                b1 = fdot2(wB[q + 1], h1, b1);
            }
            float zA = a0 + a1, zB = b0 + b1;
            float gi = 0.f, gg = 0.f;
            if (j < 128) { gi = fsig(zA); gg = ftanh(zB); }
            else         { sm[GBF + (j - 128)] = fsig(zA); sm[GBF + 128 + (j - 128)] = fsig(zB); }
            __syncthreads();
            if (j < 128) {
                float f = sm[GBF + j], o = sm[GBF + 128 + j];
                c = fmaf(f, c, gi * gg);
                sm[HBF + j] = o * ftanh(c);
            }
            __syncthreads();
            hpk = pk16(sm[HBF + 2 * ln], sm[HBF + 2 * ln + 1]);
            if (j < 64) smu[YSPK + tt * 64 + ln] = hpk;
        }
    }
    __syncthreads();
    // ---- layer1 x-part ----
    {
        unsigned wA[64], wB[64];
        const float4* ra = (const float4*)(W1ih + rowA * 128);
        const float4* rb = (const float4*)(W1ih + rowB * 128);
        #pragma unroll
        for (int k4 = 0; k4 < 32; ++k4) {
            float4 a = ra[k4], b = rb[k4];
            wA[2*k4] = pk16(a.x, a.y); wA[2*k4+1] = pk16(a.z, a.w);
            wB[2*k4] = pk16(b.x, b.y); wB[2*k4+1] = pk16(b.z, b.w);
        }
        const float biasA = b1ih[rowA] + b1hh[rowA];
        const float biasB = b1ih[rowB] + b1hh[rowB];
        for (int tt = 0; tt < kT; ++tt) {
            unsigned yv = smu[YSPK + tt * 64 + ln];
            float a0 = biasA, a1 = 0.f, b0 = biasB, b1 = 0.f;
            #pragma unroll
            for (int q = 0; q < 64; q += 2) {
                unsigned y0 = rlu(yv, q), y1 = rlu(yv, q + 1);
                a0 = fdot2(wA[q],     y0, a0);
                a1 = fdot2(wA[q + 1], y1, a1);
                b0 = fdot2(wB[q],     y0, b0);
                b1 = fdot2(wB[q + 1], y1, b1);
            }
            sm[ZX + tt * 512 + rowA] = a0 + a1;
            sm[ZX + tt * 512 + rowB] = b0 + b1;
        }
    }
    __syncthreads();
    // ---- layer1 recurrence (final h left in HBF) ----
    {
        unsigned wA[64], wB[64];
        const float4* ra = (const float4*)(W1hh + rowA * 128);
        const float4* rb = (const float4*)(W1hh + rowB * 128);
        #pragma unroll
        for (int k4 = 0; k4 < 32; ++k4) {
            float4 a = ra[k4], b = rb[k4];
            wA[2*k4] = pk16(a.x, a.y); wA[2*k4+1] = pk16(a.z, a.w);
            wB[2*k4] = pk16(b.x, b.y); wB[2*k4+1] = pk16(b.z, b.w);
        }
        unsigned hpk = 0;
        float c = 0.f;
        for (int tt = 0; tt < kT; ++tt) {
            float a0 = sm[ZX + tt * 512 + rowA], a1 = 0.f;
            float b0 = sm[ZX + tt * 512 + rowB], b1 = 0.f;
            #pragma unroll
            for (int q = 0; q < 64; q += 2) {
                unsigned h0 = rlu(hpk, q), h1 = rlu(hpk, q + 1);
                a0 = fdot2(wA[q],     h0, a0);
                a1 = fdot2(wA[q + 1], h1, a1);
                b0 = fdot2(wB[q],     h0, b0);
                b1 = fdot2(wB[q + 1], h1, b1);
            }
            float zA = a0 + a1, zB = b0 + b1;
            float gi = 0.f, gg = 0.f;
            if (j < 128) { gi = fsig(zA); gg = ftanh(zB); }
            else         { sm[GBF + (j - 128)] = fsig(zA); sm[GBF + 128 + (j - 128)] = fsig(zB); }
            __syncthreads();
            if (j < 128) {
                float f = sm[GBF + j], o = sm[GBF + 128 + j];
                c = fmaf(f, c, gi * gg);
                sm[HBF + j] = o * ftanh(c);
            }
            __syncthreads();
            hpk = pk16(sm[HBF + 2 * ln], sm[HBF + 2 * ln + 1]);
        }
    }
    // ---- MLP head ----
    if (j < 64) {
        float a0 = hb1[j], a1 = 0.f;
        #pragma unroll 8
        for (int k = 0; k < 128; k += 2) {
            a0 = fmaf(hW1[j * 128 + k],     sm[HBF + k],     a0);
            a1 = fmaf(hW1[j * 128 + k + 1], sm[HBF + k + 1], a1);
        }
        sm[ES + j] = fmaxf(a0 + a1, 0.f);
    }
    __syncthreads();
    if (j < 32) {
        float acc = hb2[j];
        #pragma unroll 8
        for (int k = 0; k < 64; ++k) acc = fmaf(hW2[j * 64 + k], sm[ES + k], acc);
        sm[ES + 64 + j] = fmaxf(acc, 0.f);
    }
    __syncthreads();
    if (j == 0) {
        float acc = hb3[0];
        #pragma unroll
        for (int k = 0; k < 32; ++k) acc = fmaf(hW3[k], sm[ES + 64 + k], acc);
        outp[bb] = fsig(acc);
    }
}

extern "C" void kernel_launch(void* const* d_in, const int* in_sizes, int n_in,
                              void* d_out, int out_size, void* d_ws, size_t ws_size,
                              hipStream_t stream) {
    const float* x     = (const float*)d_in[0];
    const int*   eidx  = (const int*)  d_in[1];
    const float* projW = (const float*)d_in[2];
    const float* projb = (const float*)d_in[3];
    const float* gWl   = (const float*)d_in[4];
    const float* gWr   = (const float*)d_in[5];
    const float* gatt  = (const float*)d_in[6];
    const float* gb    = (const float*)d_in[7];
    const float* lng   = (const float*)d_in[8];
    const float* lnb   = (const float*)d_in[9];
    const float* W0ih  = (const float*)d_in[10];
    const float* W0hh  = (const float*)d_in[11];
    const float* b0ih  = (const float*)d_in[12];
    const float* b0hh  = (const float*)d_in[13];
    const float* W1ih  = (const float*)d_in[14];
    const float* W1hh  = (const float*)d_in[15];
    const float* b1ih  = (const float*)d_in[16];
    const float* b1hh  = (const float*)d_in[17];
    const float* hW1   = (const float*)d_in[18];
    const float* hb1   = (const float*)d_in[19];
    const float* hW2   = (const float*)d_in[20];
    const float* hb2   = (const float*)d_in[21];
    const float* hW3   = (const float*)d_in[22];
    const float* hb3   = (const float*)d_in[23];
    float* outp = (float*)d_out;
    float* emb  = (float*)d_ws;   // [512][64] fp32 scratch

    (void)hipFuncSetAttribute((const void*)gat_kernel,
                              hipFuncAttributeMaxDynamicSharedMemorySize, (int)GAT_LDS);
    (void)hipFuncSetAttribute((const void*)lstm_head_kernel,
                              hipFuncAttributeMaxDynamicSharedMemorySize, (int)LSTM_LDS);

    hipLaunchKernelGGL(gat_kernel, dim3(kG), dim3(512), GAT_LDS, stream,
                       x, eidx, projW, projb, gWl, gWr, gatt, gb, lng, lnb, emb);
    hipLaunchKernelGGL(lstm_head_kernel, dim3(kB), dim3(256), LSTM_LDS, stream,
                       emb, W0ih, W0hh, b0ih, b0hh, W1ih, W1hh, b1ih, b1hh,
                       hW1, hb1, hW2, hb2, hW3, hb3, outp);
}